// Round 1
// baseline (5114.123 us; speedup 1.0000x reference)
//
#include <hip/hip_runtime.h>

#define NNODES 50000
#define HDIM 6
#define KTOT (NNODES * HDIM)   // 300000
#define BGR 32
#define BN_EPS 1e-5f
#define KC 1024
#define KS 64

// ---------- degree / normalization ----------
__global__ void count_deg_kernel(const int* __restrict__ col, int E, int* __restrict__ deg) {
    int e = blockIdx.x * blockDim.x + threadIdx.x;
    if (e < E) atomicAdd(&deg[col[e]], 1);
}

__global__ void make_dis_kernel(const int* __restrict__ deg, float* __restrict__ dis, int N) {
    int n = blockIdx.x * blockDim.x + threadIdx.x;
    if (n < N) dis[n] = rsqrtf((float)(deg[n] + 1));   // +1 self loop; always > 0
}

// ---------- transform: m = h @ W ; agg_init = m * dis[n]^2 (self-loop term) ----------
// NOTE: h and agg may alias (in-place row overwrite after full row read) -> no __restrict__ on them.
__global__ void transform_kernel(const float* h, int KD,
                                 const float* __restrict__ W,
                                 const float* __restrict__ dis,
                                 float* __restrict__ m, float* agg,
                                 int NB, int N) {
    __shared__ float sW[6 * HDIM];
    int tid = threadIdx.x;
    if (tid < KD * HDIM) sW[tid] = W[tid];
    __syncthreads();
    int i = blockIdx.x * blockDim.x + tid;
    if (i >= NB) return;
    int n = i % N;
    float hl[6];
    const float* hr = h + (size_t)i * KD;
    for (int k = 0; k < KD; k++) hl[k] = hr[k];
    float d = dis[n];
    float d2 = d * d;
    float ml[HDIM];
    #pragma unroll
    for (int j = 0; j < HDIM; j++) {
        float a = 0.f;
        for (int k = 0; k < KD; k++) a += hl[k] * sW[k * HDIM + j];
        ml[j] = a;
    }
    float* mr = m + (size_t)i * HDIM;
    float* ar = agg + (size_t)i * HDIM;
    #pragma unroll
    for (int j = 0; j < HDIM; j++) { mr[j] = ml[j]; ar[j] = ml[j] * d2; }
}

// ---------- edge scatter: agg[col] += m[row] * dis[row] * dis[col] ----------
__global__ void scatter_kernel(const int* __restrict__ row, const int* __restrict__ col,
                               const float* __restrict__ dis,
                               const float* __restrict__ m, float* __restrict__ agg,
                               int E, int N) {
    int e = blockIdx.x * blockDim.x + threadIdx.x;
    if (e >= E) return;
    int b = blockIdx.y;
    int r = row[e], c = col[e];
    float w = dis[r] * dis[c];
    const float* mr = m + ((size_t)b * N + r) * HDIM;
    float* ar = agg + ((size_t)b * N + c) * HDIM;
    #pragma unroll
    for (int j = 0; j < HDIM; j++) atomicAdd(&ar[j], mr[j] * w);
}

// ---------- BN stats: per-channel sum and sumsq over NB rows ----------
__global__ void stats_kernel(const float* __restrict__ agg, int NB, float* __restrict__ stats) {
    float s[HDIM], ss[HDIM];
    #pragma unroll
    for (int j = 0; j < HDIM; j++) { s[j] = 0.f; ss[j] = 0.f; }
    for (int i = blockIdx.x * blockDim.x + threadIdx.x; i < NB; i += gridDim.x * blockDim.x) {
        const float* ar = agg + (size_t)i * HDIM;
        #pragma unroll
        for (int j = 0; j < HDIM; j++) { float v = ar[j]; s[j] += v; ss[j] += v * v; }
    }
    #pragma unroll
    for (int off = 32; off > 0; off >>= 1) {
        #pragma unroll
        for (int j = 0; j < HDIM; j++) {
            s[j] += __shfl_down(s[j], off, 64);
            ss[j] += __shfl_down(ss[j], off, 64);
        }
    }
    __shared__ float red[4][2 * HDIM];
    int lane = threadIdx.x & 63, w = threadIdx.x >> 6;
    if (lane == 0) {
        #pragma unroll
        for (int j = 0; j < HDIM; j++) { red[w][j] = s[j]; red[w][HDIM + j] = ss[j]; }
    }
    __syncthreads();
    if (threadIdx.x < 2 * HDIM) {
        float a = red[0][threadIdx.x] + red[1][threadIdx.x] + red[2][threadIdx.x] + red[3][threadIdx.x];
        atomicAdd(&stats[threadIdx.x], a);
    }
}

// ---------- BN + ReLU (conv bias cancels inside BN) ----------
__global__ void bn_relu_kernel(const float* __restrict__ agg, const float* __restrict__ stats,
                               const float* __restrict__ g, const float* __restrict__ be,
                               float* __restrict__ out, int NB) {
    int i = blockIdx.x * blockDim.x + threadIdx.x;
    if (i >= NB) return;
    float inv = 1.0f / (float)NB;
    const float* ar = agg + (size_t)i * HDIM;
    float* orow = out + (size_t)i * HDIM;
    #pragma unroll
    for (int j = 0; j < HDIM; j++) {
        float mu = stats[j] * inv;
        float var = stats[HDIM + j] * inv - mu * mu;
        float rs = rsqrtf(var + BN_EPS);
        float v = g[j] * (ar[j] - mu) * rs + be[j];
        orow[j] = v > 0.f ? v : 0.f;
    }
}

// ---------- GEMM1: out1[b][c] += sum_k act[b][k] * lw1[k][c]   (split-K, atomic accumulate) ----------
__global__ __launch_bounds__(256) void gemm1_kernel(const float* __restrict__ act,
                                                    const float* __restrict__ lw1,
                                                    float* __restrict__ out1) {
    __shared__ float s_act[BGR * KS];
    int tid = threadIdx.x;
    int k0 = blockIdx.x * KC;
    float acc[BGR];
    #pragma unroll
    for (int b = 0; b < BGR; b++) acc[b] = 0.f;
    for (int ks0 = 0; ks0 < KC; ks0 += KS) {
        int kbase = k0 + ks0;
        __syncthreads();
        for (int idx = tid; idx < BGR * KS; idx += 256) {
            int b = idx / KS, kk = idx % KS;
            int k = kbase + kk;
            s_act[idx] = (k < KTOT) ? act[(size_t)b * KTOT + k] : 0.f;
        }
        __syncthreads();
        int klim = KTOT - kbase; if (klim > KS) klim = KS;
        for (int kk = 0; kk < klim; kk++) {
            float w = lw1[(size_t)(kbase + kk) * 256 + tid];
            #pragma unroll
            for (int b = 0; b < BGR; b++) acc[b] += s_act[b * KS + kk] * w;
        }
    }
    #pragma unroll
    for (int b = 0; b < BGR; b++) atomicAdd(&out1[b * 256 + tid], acc[b]);
}

// ---------- MLP tail: relu(out1+lb1) @ lw2 -> relu -> @ lw3 -> relu -> @ lw4 ----------
__global__ __launch_bounds__(128) void mlp_tail_kernel(const float* __restrict__ out1,
                                                       const float* __restrict__ lb1,
                                                       const float* __restrict__ lw2, const float* __restrict__ lb2,
                                                       const float* __restrict__ lw3, const float* __restrict__ lb3,
                                                       const float* __restrict__ lw4, const float* __restrict__ lb4,
                                                       float* __restrict__ out) {
    __shared__ float s1[256], s2[128], s3[64];
    int b = blockIdx.x;
    int tid = threadIdx.x;
    for (int c = tid; c < 256; c += 128) {
        float v = out1[b * 256 + c] + lb1[c];
        s1[c] = v > 0.f ? v : 0.f;
    }
    __syncthreads();
    {
        float a = lb2[tid];
        for (int k = 0; k < 256; k++) a += s1[k] * lw2[k * 128 + tid];
        s2[tid] = a > 0.f ? a : 0.f;
    }
    __syncthreads();
    if (tid < 64) {
        float a = lb3[tid];
        for (int k = 0; k < 128; k++) a += s2[k] * lw3[k * 64 + tid];
        s3[tid] = a > 0.f ? a : 0.f;
    }
    __syncthreads();
    if (tid < 32) {
        float a = lb4[tid];
        for (int k = 0; k < 64; k++) a += s3[k] * lw4[k * 32 + tid];
        out[b * 32 + tid] = a;
    }
}

extern "C" void kernel_launch(void* const* d_in, const int* in_sizes, int n_in,
                              void* d_out, int out_size, void* d_ws, size_t ws_size,
                              hipStream_t stream) {
    const float* x   = (const float*)d_in[0];
    const int* edge  = (const int*)d_in[1];
    const float* W1  = (const float*)d_in[2];
    const float* g1  = (const float*)d_in[4];
    const float* be1 = (const float*)d_in[5];
    const float* W2  = (const float*)d_in[6];
    const float* g2  = (const float*)d_in[8];
    const float* be2 = (const float*)d_in[9];
    const float* W3  = (const float*)d_in[10];
    const float* g3  = (const float*)d_in[12];
    const float* be3 = (const float*)d_in[13];
    const float* lw1 = (const float*)d_in[14];
    const float* lb1 = (const float*)d_in[15];
    const float* lw2 = (const float*)d_in[16];
    const float* lb2 = (const float*)d_in[17];
    const float* lw3 = (const float*)d_in[18];
    const float* lb3 = (const float*)d_in[19];
    const float* lw4 = (const float*)d_in[20];
    const float* lb4 = (const float*)d_in[21];

    const int E = in_sizes[1] / 2;
    const int N = NNODES;
    const int B = in_sizes[0] / (N * 3);
    const int NB = B * N;

    char* ws = (char*)d_ws;
    size_t bufBytes = (size_t)NB * HDIM * sizeof(float);   // 38.4 MB
    float* bufA  = (float*)ws;
    float* bufB  = (float*)(ws + bufBytes);
    float* dis   = (float*)(ws + 2 * bufBytes);
    int*   deg   = (int*)  (ws + 2 * bufBytes + (size_t)N * 4);
    float* stats = (float*)(ws + 2 * bufBytes + 2 * (size_t)N * 4);
    float* out1  = stats + 16;

    const int T = 256;
    const int rowsGrid = (NB + T - 1) / T;
    dim3 edgeGrid((E + T - 1) / T, B);

    // degrees / dis (edges identical per graph -> compute once)
    hipMemsetAsync(deg, 0, (size_t)N * 4, stream);
    count_deg_kernel<<<(E + T - 1) / T, T, 0, stream>>>(edge + E, E, deg);
    make_dis_kernel<<<(N + T - 1) / T, T, 0, stream>>>(deg, dis, N);

    // ---- layer 1: h = x (3-wide), m -> bufB, agg -> bufA, out(h1) -> bufB
    transform_kernel<<<rowsGrid, T, 0, stream>>>(x, 3, W1, dis, bufB, bufA, NB, N);
    scatter_kernel<<<edgeGrid, T, 0, stream>>>(edge, edge + E, dis, bufB, bufA, E, N);
    hipMemsetAsync(stats, 0, 64, stream);
    stats_kernel<<<2048, T, 0, stream>>>(bufA, NB, stats);
    bn_relu_kernel<<<rowsGrid, T, 0, stream>>>(bufA, stats, g1, be1, bufB, NB);

    // ---- layer 2: h = bufB, m -> bufA, agg -> bufB (in place), out(h2) -> bufA
    transform_kernel<<<rowsGrid, T, 0, stream>>>(bufB, HDIM, W2, dis, bufA, bufB, NB, N);
    scatter_kernel<<<edgeGrid, T, 0, stream>>>(edge, edge + E, dis, bufA, bufB, E, N);
    hipMemsetAsync(stats, 0, 64, stream);
    stats_kernel<<<2048, T, 0, stream>>>(bufB, NB, stats);
    bn_relu_kernel<<<rowsGrid, T, 0, stream>>>(bufB, stats, g2, be2, bufA, NB);

    // ---- layer 3: h = bufA, m -> bufB, agg -> bufA (in place), out(h3) -> bufB
    transform_kernel<<<rowsGrid, T, 0, stream>>>(bufA, HDIM, W3, dis, bufB, bufA, NB, N);
    scatter_kernel<<<edgeGrid, T, 0, stream>>>(edge, edge + E, dis, bufB, bufA, E, N);
    hipMemsetAsync(stats, 0, 64, stream);
    stats_kernel<<<2048, T, 0, stream>>>(bufA, NB, stats);
    bn_relu_kernel<<<rowsGrid, T, 0, stream>>>(bufA, stats, g3, be3, bufB, NB);

    // ---- MLP: act = bufB (layout [B*N][6] == [B][300000] flat)
    hipMemsetAsync(out1, 0, (size_t)B * 256 * sizeof(float), stream);
    gemm1_kernel<<<(KTOT + KC - 1) / KC, T, 0, stream>>>(bufB, lw1, out1);
    mlp_tail_kernel<<<B, 128, 0, stream>>>(out1, lb1, lw2, lb2, lw3, lb3, lw4, lb4, (float*)d_out);
}

// Round 2
// 877.594 us; speedup vs baseline: 5.8274x; 5.8274x over previous
//
#include <hip/hip_runtime.h>

#define NNODES 50000
#define HDIM 6
#define KTOT (NNODES * HDIM)   // 300000
#define BGR 32
#define BN_EPS 1e-5f
#define KC2 512
#define KS 64
#define SPLITS ((KTOT + KC2 - 1) / KC2)   // 586

// ---------- degree / normalization ----------
__global__ void count_deg_kernel(const int* __restrict__ col, int E, int* __restrict__ deg) {
    int e = blockIdx.x * blockDim.x + threadIdx.x;
    if (e < E) atomicAdd(&deg[col[e]], 1);
}

__global__ void make_dis_kernel(const int* __restrict__ deg, float* __restrict__ dis, int N) {
    int n = blockIdx.x * blockDim.x + threadIdx.x;
    if (n < N) dis[n] = rsqrtf((float)(deg[n] + 1));   // +1 self loop; always > 0
}

// ---------- exclusive scan of deg -> offsets (and cursor copy), single block ----------
__global__ __launch_bounds__(1024) void scan_kernel(const int* __restrict__ deg,
                                                    int* __restrict__ offsets,
                                                    int* __restrict__ cursor, int N) {
    __shared__ int lds[1024];
    const int CH = (NNODES + 1023) / 1024;   // 49
    int tid = threadIdx.x;
    int start = tid * CH, end = start + CH; if (end > N) end = N; if (start > N) start = N;
    int s = 0;
    for (int i = start; i < end; i++) s += deg[i];
    lds[tid] = s;
    __syncthreads();
    for (int off = 1; off < 1024; off <<= 1) {
        int v = (tid >= off) ? lds[tid - off] : 0;
        __syncthreads();
        lds[tid] += v;
        __syncthreads();
    }
    int base = (tid == 0) ? 0 : lds[tid - 1];
    for (int i = start; i < end; i++) { offsets[i] = base; cursor[i] = base; base += deg[i]; }
    if (tid == 1023) offsets[N] = lds[1023];
}

// ---------- CSR fill: group edges by destination; precompute edge weight ----------
__global__ void fill_csr_kernel(const int* __restrict__ row, const int* __restrict__ col,
                                const float* __restrict__ dis, int* __restrict__ cursor,
                                int* __restrict__ csr_row, float* __restrict__ csr_w, int E) {
    int e = blockIdx.x * blockDim.x + threadIdx.x;
    if (e >= E) return;
    int r = row[e], c = col[e];
    int pos = atomicAdd(&cursor[c], 1);
    csr_row[pos] = r;
    csr_w[pos] = dis[r] * dis[c];
}

// ---------- layer-1 transform: m = x @ W1 (x is 3-wide) ----------
__global__ void transform1_kernel(const float* __restrict__ x, const float* __restrict__ W,
                                  float* __restrict__ m, int NB) {
    __shared__ float sW[3 * HDIM];
    if (threadIdx.x < 3 * HDIM) sW[threadIdx.x] = W[threadIdx.x];
    __syncthreads();
    int i = blockIdx.x * blockDim.x + threadIdx.x;
    if (i >= NB) return;
    float h0 = x[3 * (size_t)i], h1 = x[3 * (size_t)i + 1], h2 = x[3 * (size_t)i + 2];
    float* mr = m + (size_t)i * HDIM;
    #pragma unroll
    for (int j = 0; j < HDIM; j++)
        mr[j] = h0 * sW[j] + h1 * sW[HDIM + j] + h2 * sW[2 * HDIM + j];
}

// ---------- gather: agg[b][n] = d2*m[b][n] + sum_in w_e * m[b][r]; fused BN stats ----------
__global__ __launch_bounds__(256) void gather_kernel(const float* __restrict__ m,
                                                     const int* __restrict__ offsets,
                                                     const int* __restrict__ csr_row,
                                                     const float* __restrict__ csr_w,
                                                     const float* __restrict__ dis,
                                                     float* __restrict__ agg,
                                                     float* __restrict__ stats, int N) {
    int tid = threadIdx.x;
    int n = blockIdx.x * 256 + tid;
    int b = blockIdx.y;
    float acc[HDIM] = {0.f, 0.f, 0.f, 0.f, 0.f, 0.f};
    if (n < N) {
        const float* mg = m + (size_t)b * N * HDIM;
        float d = dis[n];
        float d2 = d * d;
        const float* mc = mg + (size_t)n * HDIM;
        #pragma unroll
        for (int j = 0; j < HDIM; j++) acc[j] = mc[j] * d2;
        int s = offsets[n], e2 = offsets[n + 1];
        for (int p = s; p < e2; p++) {
            int r = csr_row[p];
            float w = csr_w[p];
            const float* mr = mg + (size_t)r * HDIM;
            #pragma unroll
            for (int j = 0; j < HDIM; j++) acc[j] += mr[j] * w;
        }
        float* ar = agg + ((size_t)b * N + n) * HDIM;
        #pragma unroll
        for (int j = 0; j < HDIM; j++) ar[j] = acc[j];
    }
    // BN stats: sum and sumsq per channel (rows with n>=N contribute zeros)
    float s0[HDIM], ss[HDIM];
    #pragma unroll
    for (int j = 0; j < HDIM; j++) { s0[j] = acc[j]; ss[j] = acc[j] * acc[j]; }
    #pragma unroll
    for (int off = 32; off > 0; off >>= 1) {
        #pragma unroll
        for (int j = 0; j < HDIM; j++) {
            s0[j] += __shfl_down(s0[j], off, 64);
            ss[j] += __shfl_down(ss[j], off, 64);
        }
    }
    __shared__ float red[4][2 * HDIM];
    int lane = tid & 63, w = tid >> 6;
    if (lane == 0) {
        #pragma unroll
        for (int j = 0; j < HDIM; j++) { red[w][j] = s0[j]; red[w][HDIM + j] = ss[j]; }
    }
    __syncthreads();
    if (tid < 2 * HDIM) {
        float a = red[0][tid] + red[1][tid] + red[2][tid] + red[3][tid];
        atomicAdd(&stats[tid], a);
    }
}

// ---------- fused BN + ReLU + transform: m_next = relu(bn(agg)) @ W ----------
__global__ void bn_transform_kernel(const float* __restrict__ agg, const float* __restrict__ stats,
                                    const float* __restrict__ g, const float* __restrict__ be,
                                    const float* __restrict__ W, float* __restrict__ m, int NB) {
    __shared__ float sW[HDIM * HDIM];
    __shared__ float sa[HDIM], sc[HDIM];
    int tid = threadIdx.x;
    if (tid < HDIM * HDIM) sW[tid] = W[tid];
    if (tid < HDIM) {
        float inv = 1.0f / (float)NB;
        float mu = stats[tid] * inv;
        float var = stats[HDIM + tid] * inv - mu * mu;
        float rs = rsqrtf(var + BN_EPS);
        float a = g[tid] * rs;
        sa[tid] = a;
        sc[tid] = be[tid] - mu * a;
    }
    __syncthreads();
    int i = blockIdx.x * blockDim.x + tid;
    if (i >= NB) return;
    const float* ar = agg + (size_t)i * HDIM;
    float h[HDIM];
    #pragma unroll
    for (int j = 0; j < HDIM; j++) {
        float v = fmaf(sa[j], ar[j], sc[j]);
        h[j] = v > 0.f ? v : 0.f;
    }
    float* mr = m + (size_t)i * HDIM;
    #pragma unroll
    for (int j = 0; j < HDIM; j++) {
        float a = 0.f;
        #pragma unroll
        for (int k = 0; k < HDIM; k++) a += h[k] * sW[k * HDIM + j];
        mr[j] = a;
    }
}

// ---------- GEMM1 split-K with fused layer-3 BN+ReLU; deterministic partials ----------
__global__ __launch_bounds__(256) void gemm1_kernel(const float* __restrict__ agg,
                                                    const float* __restrict__ stats,
                                                    const float* __restrict__ g,
                                                    const float* __restrict__ be,
                                                    const float* __restrict__ lw1,
                                                    float* __restrict__ partials, int NB) {
    __shared__ float s_act[BGR * KS];
    __shared__ float sa[HDIM], sc[HDIM];
    int tid = threadIdx.x;
    if (tid < HDIM) {
        float inv = 1.0f / (float)NB;
        float mu = stats[tid] * inv;
        float var = stats[HDIM + tid] * inv - mu * mu;
        float rs = rsqrtf(var + BN_EPS);
        float a = g[tid] * rs;
        sa[tid] = a;
        sc[tid] = be[tid] - mu * a;
    }
    __syncthreads();
    int k0 = blockIdx.x * KC2;
    float acc[BGR];
    #pragma unroll
    for (int b = 0; b < BGR; b++) acc[b] = 0.f;
    for (int ks0 = 0; ks0 < KC2; ks0 += KS) {
        int kbase = k0 + ks0;
        __syncthreads();
        for (int idx = tid; idx < BGR * KS; idx += 256) {
            int b = idx >> 6, kk = idx & 63;
            int k = kbase + kk;
            float v = 0.f;
            if (k < KTOT) {
                int j = k % HDIM;
                float t = fmaf(sa[j], agg[(size_t)b * KTOT + k], sc[j]);
                v = t > 0.f ? t : 0.f;
            }
            s_act[idx] = v;
        }
        __syncthreads();
        int klim = KTOT - kbase; if (klim > KS) klim = KS; if (klim < 0) klim = 0;
        for (int kk = 0; kk < klim; kk++) {
            float w = lw1[(size_t)(kbase + kk) * 256 + tid];
            #pragma unroll
            for (int b = 0; b < BGR; b++) acc[b] += s_act[b * KS + kk] * w;
        }
    }
    #pragma unroll
    for (int b = 0; b < BGR; b++)
        partials[((size_t)blockIdx.x * BGR + b) * 256 + tid] = acc[b];
}

// ---------- tail: reduce partials + lb1/relu, then 256->128->64->32 ----------
__global__ __launch_bounds__(1024) void tail_kernel(const float* __restrict__ partials,
                                                    const float* __restrict__ lb1,
                                                    const float* __restrict__ lw2, const float* __restrict__ lb2,
                                                    const float* __restrict__ lw3, const float* __restrict__ lb3,
                                                    const float* __restrict__ lw4, const float* __restrict__ lb4,
                                                    float* __restrict__ out) {
    __shared__ float red[4][256];
    __shared__ float s1[256], s2[128], s3[64];
    int b = blockIdx.x;
    int tid = threadIdx.x;
    int c = tid & 255, sg = tid >> 8;
    float a = 0.f;
    for (int s = sg; s < SPLITS; s += 4)
        a += partials[((size_t)s * BGR + b) * 256 + c];
    red[sg][c] = a;
    __syncthreads();
    if (tid < 256) {
        float v = red[0][tid] + red[1][tid] + red[2][tid] + red[3][tid] + lb1[tid];
        s1[tid] = v > 0.f ? v : 0.f;
    }
    __syncthreads();
    if (tid < 128) {
        float acc = lb2[tid];
        for (int k = 0; k < 256; k++) acc += s1[k] * lw2[k * 128 + tid];
        s2[tid] = acc > 0.f ? acc : 0.f;
    }
    __syncthreads();
    if (tid < 64) {
        float acc = lb3[tid];
        for (int k = 0; k < 128; k++) acc += s2[k] * lw3[k * 64 + tid];
        s3[tid] = acc > 0.f ? acc : 0.f;
    }
    __syncthreads();
    if (tid < 32) {
        float acc = lb4[tid];
        for (int k = 0; k < 64; k++) acc += s3[k] * lw4[k * 32 + tid];
        out[b * 32 + tid] = acc;
    }
}

extern "C" void kernel_launch(void* const* d_in, const int* in_sizes, int n_in,
                              void* d_out, int out_size, void* d_ws, size_t ws_size,
                              hipStream_t stream) {
    const float* x   = (const float*)d_in[0];
    const int* edge  = (const int*)d_in[1];
    const float* W1  = (const float*)d_in[2];
    const float* g1  = (const float*)d_in[4];
    const float* be1 = (const float*)d_in[5];
    const float* W2  = (const float*)d_in[6];
    const float* g2  = (const float*)d_in[8];
    const float* be2 = (const float*)d_in[9];
    const float* W3  = (const float*)d_in[10];
    const float* g3  = (const float*)d_in[12];
    const float* be3 = (const float*)d_in[13];
    const float* lw1 = (const float*)d_in[14];
    const float* lb1 = (const float*)d_in[15];
    const float* lw2 = (const float*)d_in[16];
    const float* lb2 = (const float*)d_in[17];
    const float* lw3 = (const float*)d_in[18];
    const float* lb3 = (const float*)d_in[19];
    const float* lw4 = (const float*)d_in[20];
    const float* lb4 = (const float*)d_in[21];

    const int E = in_sizes[1] / 2;
    const int N = NNODES;
    const int B = in_sizes[0] / (N * 3);
    const int NB = B * N;

    char* ws = (char*)d_ws;
    size_t bufBytes = (size_t)NB * HDIM * sizeof(float);   // 38.4 MB
    float* bufM   = (float*)ws;                            // m (transformed); later aliased by partials
    float* bufAgg = (float*)(ws + bufBytes);
    char* p = ws + 2 * bufBytes;
    float* dis    = (float*)p;                 p += (size_t)N * 4;
    int*   deg    = (int*)p;                   p += (size_t)N * 4;
    int*   offs   = (int*)p;                   p += (size_t)(N + 1) * 4;
    int*   cursor = (int*)p;                   p += (size_t)N * 4;
    int*   csr_row= (int*)p;                   p += (size_t)E * 4;
    float* csr_w  = (float*)p;                 p += (size_t)E * 4;
    float* stats  = (float*)p;                 p += 48 * 4;   // 3 layers x 16 slots
    float* stats1 = stats, *stats2 = stats + 16, *stats3 = stats + 32;
    float* partials = bufM;   // gemm1 no longer needs m; 586*32*256*4 = 19.2 MB < 38.4 MB

    const int T = 256;
    const int rowsGrid = (NB + T - 1) / T;
    dim3 gatherGrid((N + T - 1) / T, B);

    hipMemsetAsync(deg, 0, (size_t)N * 4, stream);
    hipMemsetAsync(stats, 0, 48 * 4, stream);
    count_deg_kernel<<<(E + T - 1) / T, T, 0, stream>>>(edge + E, E, deg);
    make_dis_kernel<<<(N + T - 1) / T, T, 0, stream>>>(deg, dis, N);
    scan_kernel<<<1, 1024, 0, stream>>>(deg, offs, cursor, N);
    fill_csr_kernel<<<(E + T - 1) / T, T, 0, stream>>>(edge, edge + E, dis, cursor, csr_row, csr_w, E);

    // layer 1
    transform1_kernel<<<rowsGrid, T, 0, stream>>>(x, W1, bufM, NB);
    gather_kernel<<<gatherGrid, T, 0, stream>>>(bufM, offs, csr_row, csr_w, dis, bufAgg, stats1, N);
    // layer 2 (BN1+ReLU fused with W2 transform)
    bn_transform_kernel<<<rowsGrid, T, 0, stream>>>(bufAgg, stats1, g1, be1, W2, bufM, NB);
    gather_kernel<<<gatherGrid, T, 0, stream>>>(bufM, offs, csr_row, csr_w, dis, bufAgg, stats2, N);
    // layer 3
    bn_transform_kernel<<<rowsGrid, T, 0, stream>>>(bufAgg, stats2, g2, be2, W3, bufM, NB);
    gather_kernel<<<gatherGrid, T, 0, stream>>>(bufM, offs, csr_row, csr_w, dis, bufAgg, stats3, N);

    // MLP head: gemm1 reads bufAgg with fused BN3+ReLU
    gemm1_kernel<<<SPLITS, T, 0, stream>>>(bufAgg, stats3, g3, be3, lw1, partials, NB);
    tail_kernel<<<B, 1024, 0, stream>>>(partials, lb1, lw2, lb2, lw3, lb3, lw4, lb4, (float*)d_out);
}

// Round 3
// 685.617 us; speedup vs baseline: 7.4592x; 1.2800x over previous
//
#include <hip/hip_runtime.h>

#define NNODES 50000
#define HDIM 6
#define KTOT (NNODES * HDIM)   // 300000
#define BGR 32
#define BN_EPS 1e-5f
#define KC2 512
#define SPLITS ((KTOT + KC2 - 1) / KC2)   // 586

// ---------- degree / normalization ----------
__global__ void count_deg_kernel(const int* __restrict__ col, int E, int* __restrict__ deg) {
    int e = blockIdx.x * blockDim.x + threadIdx.x;
    if (e < E) atomicAdd(&deg[col[e]], 1);
}

__global__ void make_dis_kernel(const int* __restrict__ deg, float* __restrict__ dis, int N) {
    int n = blockIdx.x * blockDim.x + threadIdx.x;
    if (n < N) dis[n] = rsqrtf((float)(deg[n] + 1));   // +1 self loop; always > 0
}

// ---------- exclusive scan of deg -> offsets (and cursor copy), single block ----------
__global__ __launch_bounds__(1024) void scan_kernel(const int* __restrict__ deg,
                                                    int* __restrict__ offsets,
                                                    int* __restrict__ cursor, int N) {
    __shared__ int lds[1024];
    const int CH = (NNODES + 1023) / 1024;   // 49
    int tid = threadIdx.x;
    int start = tid * CH, end = start + CH; if (end > N) end = N; if (start > N) start = N;
    int s = 0;
    for (int i = start; i < end; i++) s += deg[i];
    lds[tid] = s;
    __syncthreads();
    for (int off = 1; off < 1024; off <<= 1) {
        int v = (tid >= off) ? lds[tid - off] : 0;
        __syncthreads();
        lds[tid] += v;
        __syncthreads();
    }
    int base = (tid == 0) ? 0 : lds[tid - 1];
    for (int i = start; i < end; i++) { offsets[i] = base; cursor[i] = base; base += deg[i]; }
    if (tid == 1023) offsets[N] = lds[1023];
}

// ---------- CSR fill: group edges by destination; precompute edge weight ----------
__global__ void fill_csr_kernel(const int* __restrict__ row, const int* __restrict__ col,
                                const float* __restrict__ dis, int* __restrict__ cursor,
                                int* __restrict__ csr_row, float* __restrict__ csr_w, int E) {
    int e = blockIdx.x * blockDim.x + threadIdx.x;
    if (e >= E) return;
    int r = row[e], c = col[e];
    int pos = atomicAdd(&cursor[c], 1);
    csr_row[pos] = r;
    csr_w[pos] = dis[r] * dis[c];
}

// ---------- fused gather: agg[b][n] = sum_{edges+self} w * T(prev[b][r]) ----------
// T(row) = relu(bn(row)) @ W  (or row @ W for layer 1). Also emits BN stats of agg.
// Each thread handles one node for 4 consecutive graphs.
template<int KD, bool USEBN>
__global__ __launch_bounds__(256) void gatherF_kernel(
    const float* __restrict__ prev,       // [B][N][KD]
    const float* __restrict__ W,          // [KD][6]
    const float* __restrict__ stats_in,   // [12] sums/sumsq of prev layer (if USEBN)
    const float* __restrict__ gam, const float* __restrict__ bet,
    const int* __restrict__ offs, const int* __restrict__ csr_row,
    const float* __restrict__ csr_w, const float* __restrict__ dis,
    float* __restrict__ agg,              // [B][N][6]
    float* __restrict__ stats_out, int N, int NB)
{
    // uniform params (thread-invariant loads -> scalarized)
    float sw[KD * 6];
    #pragma unroll
    for (int i = 0; i < KD * 6; i++) sw[i] = W[i];
    float sa[6], sc[6];
    if constexpr (USEBN) {
        float inv = 1.f / (float)NB;
        #pragma unroll
        for (int j = 0; j < 6; j++) {
            float mu = stats_in[j] * inv;
            float var = stats_in[6 + j] * inv - mu * mu;
            float rs = rsqrtf(var + BN_EPS);
            float a = gam[j] * rs;
            sa[j] = a;
            sc[j] = bet[j] - mu * a;
        }
    }
    int tid = threadIdx.x;
    int n = blockIdx.x * 256 + tid;
    int bg = blockIdx.y * 4;
    float acc[4][6];
    #pragma unroll
    for (int g2 = 0; g2 < 4; g2++)
        #pragma unroll
        for (int j = 0; j < 6; j++) acc[g2][j] = 0.f;

    if (n < N) {
        float d = dis[n];
        int s = offs[n], e = offs[n + 1];
        int r = n;
        float wcur = d * d;            // self-loop weight first, then edges
        int p = s - 1;
        while (true) {
            float hh[4][6];
            #pragma unroll
            for (int g2 = 0; g2 < 4; g2++) {
                const float* pr = prev + ((size_t)(bg + g2) * N + r) * KD;
                if constexpr (KD == 6) {
                    const float2* p2 = (const float2*)pr;
                    float2 a0 = p2[0], a1 = p2[1], a2 = p2[2];
                    hh[g2][0] = a0.x; hh[g2][1] = a0.y; hh[g2][2] = a1.x;
                    hh[g2][3] = a1.y; hh[g2][4] = a2.x; hh[g2][5] = a2.y;
                } else {
                    hh[g2][0] = pr[0]; hh[g2][1] = pr[1]; hh[g2][2] = pr[2];
                }
            }
            #pragma unroll
            for (int g2 = 0; g2 < 4; g2++) {
                float h[KD];
                #pragma unroll
                for (int k = 0; k < KD; k++) {
                    float v = hh[g2][k];
                    if constexpr (USEBN) {
                        v = fmaf(sa[k], v, sc[k]);
                        v = v > 0.f ? v : 0.f;
                    }
                    h[k] = v;
                }
                #pragma unroll
                for (int j = 0; j < 6; j++) {
                    float t = 0.f;
                    #pragma unroll
                    for (int k = 0; k < KD; k++) t = fmaf(h[k], sw[k * 6 + j], t);
                    acc[g2][j] = fmaf(wcur, t, acc[g2][j]);
                }
            }
            p++;
            if (p >= e) break;
            r = csr_row[p];
            wcur = csr_w[p];
        }
        #pragma unroll
        for (int g2 = 0; g2 < 4; g2++) {
            float2* a2 = (float2*)(agg + ((size_t)(bg + g2) * N + n) * 6);
            a2[0] = make_float2(acc[g2][0], acc[g2][1]);
            a2[1] = make_float2(acc[g2][2], acc[g2][3]);
            a2[2] = make_float2(acc[g2][4], acc[g2][5]);
        }
    }
    // BN stats (threads with n>=N contribute zeros)
    float s0[6], ssq[6];
    #pragma unroll
    for (int j = 0; j < 6; j++) {
        s0[j] = acc[0][j] + acc[1][j] + acc[2][j] + acc[3][j];
        ssq[j] = acc[0][j] * acc[0][j] + acc[1][j] * acc[1][j]
               + acc[2][j] * acc[2][j] + acc[3][j] * acc[3][j];
    }
    #pragma unroll
    for (int off = 32; off > 0; off >>= 1) {
        #pragma unroll
        for (int j = 0; j < 6; j++) {
            s0[j] += __shfl_down(s0[j], off, 64);
            ssq[j] += __shfl_down(ssq[j], off, 64);
        }
    }
    __shared__ float red[4][12];
    int lane = tid & 63, wv = tid >> 6;
    if (lane == 0) {
        #pragma unroll
        for (int j = 0; j < 6; j++) { red[wv][j] = s0[j]; red[wv][6 + j] = ssq[j]; }
    }
    __syncthreads();
    if (tid < 12)
        atomicAdd(&stats_out[tid], red[0][tid] + red[1][tid] + red[2][tid] + red[3][tid]);
}

// ---------- GEMM1: partials[split][b][c] = sum_{k in split} relu(bn3(act))[b][k]*lw1[k][c] ----------
__global__ __launch_bounds__(256) void gemm1_kernel(const float* __restrict__ agg,
                                                    const float* __restrict__ stats,
                                                    const float* __restrict__ gam,
                                                    const float* __restrict__ bet,
                                                    const float* __restrict__ lw1,
                                                    float* __restrict__ partials, int NB) {
    __shared__ float s_act[64][36];         // [kk][graph], padded for b128-aligned reads
    __shared__ float4 lred[4][8][64];
    int tid = threadIdx.x;
    int w = tid >> 6, lane = tid & 63;
    float sa[6], sc[6];
    {
        float inv = 1.f / (float)NB;
        #pragma unroll
        for (int j = 0; j < 6; j++) {
            float mu = stats[j] * inv;
            float var = stats[6 + j] * inv - mu * mu;
            float rs = rsqrtf(var + BN_EPS);
            float a = gam[j] * rs;
            sa[j] = a;
            sc[j] = bet[j] - mu * a;
        }
    }
    float4 acc[BGR];
    #pragma unroll
    for (int b = 0; b < BGR; b++) acc[b] = make_float4(0.f, 0.f, 0.f, 0.f);

    int k0 = blockIdx.x * KC2;
    for (int c = 0; c < KC2; c += 64) {
        int kbase = k0 + c;
        __syncthreads();
        #pragma unroll
        for (int u = 0; u < 8; u++) {
            int idx = tid + u * 256;
            int b = idx >> 6, kk = idx & 63;
            int k = kbase + kk;
            float v = 0.f;
            if (k < KTOT) {
                int j = k % 6;
                float t = fmaf(sa[j], agg[(size_t)b * KTOT + k], sc[j]);
                v = t > 0.f ? t : 0.f;
            }
            s_act[kk][b] = v;
        }
        __syncthreads();
        int klo = 16 * w;
        #pragma unroll 4
        for (int kk = klo; kk < klo + 16; kk++) {
            int k = kbase + kk;
            float4 wv = make_float4(0.f, 0.f, 0.f, 0.f);
            if (k < KTOT) wv = *(const float4*)&lw1[(size_t)k * 256 + 4 * lane];
            #pragma unroll
            for (int q = 0; q < 8; q++) {
                float4 av = *(const float4*)&s_act[kk][4 * q];
                acc[4*q+0].x = fmaf(av.x, wv.x, acc[4*q+0].x); acc[4*q+0].y = fmaf(av.x, wv.y, acc[4*q+0].y);
                acc[4*q+0].z = fmaf(av.x, wv.z, acc[4*q+0].z); acc[4*q+0].w = fmaf(av.x, wv.w, acc[4*q+0].w);
                acc[4*q+1].x = fmaf(av.y, wv.x, acc[4*q+1].x); acc[4*q+1].y = fmaf(av.y, wv.y, acc[4*q+1].y);
                acc[4*q+1].z = fmaf(av.y, wv.z, acc[4*q+1].z); acc[4*q+1].w = fmaf(av.y, wv.w, acc[4*q+1].w);
                acc[4*q+2].x = fmaf(av.z, wv.x, acc[4*q+2].x); acc[4*q+2].y = fmaf(av.z, wv.y, acc[4*q+2].y);
                acc[4*q+2].z = fmaf(av.z, wv.z, acc[4*q+2].z); acc[4*q+2].w = fmaf(av.z, wv.w, acc[4*q+2].w);
                acc[4*q+3].x = fmaf(av.w, wv.x, acc[4*q+3].x); acc[4*q+3].y = fmaf(av.w, wv.y, acc[4*q+3].y);
                acc[4*q+3].z = fmaf(av.w, wv.z, acc[4*q+3].z); acc[4*q+3].w = fmaf(av.w, wv.w, acc[4*q+3].w);
            }
        }
    }
    // reduce 4 waves' k-partials, write partials[split][b][c]
    #pragma unroll
    for (int grp = 0; grp < 4; grp++) {
        __syncthreads();
        #pragma unroll
        for (int i = 0; i < 8; i++) lred[w][i][lane] = acc[grp * 8 + i];
        __syncthreads();
        #pragma unroll
        for (int t2 = 0; t2 < 2; t2++) {
            int idx = tid + t2 * 256;
            int i = idx >> 6, l = idx & 63;
            float4 v0 = lred[0][i][l], v1 = lred[1][i][l], v2 = lred[2][i][l], v3 = lred[3][i][l];
            float4 s;
            s.x = v0.x + v1.x + v2.x + v3.x;
            s.y = v0.y + v1.y + v2.y + v3.y;
            s.z = v0.z + v1.z + v2.z + v3.z;
            s.w = v0.w + v1.w + v2.w + v3.w;
            *(float4*)&partials[(((size_t)blockIdx.x * BGR) + grp * 8 + i) * 256 + 4 * l] = s;
        }
    }
}

// ---------- tail: reduce partials + lb1/relu, then 256->128->64->32 ----------
__global__ __launch_bounds__(1024) void tail_kernel(const float* __restrict__ partials,
                                                    const float* __restrict__ lb1,
                                                    const float* __restrict__ lw2, const float* __restrict__ lb2,
                                                    const float* __restrict__ lw3, const float* __restrict__ lb3,
                                                    const float* __restrict__ lw4, const float* __restrict__ lb4,
                                                    float* __restrict__ out) {
    __shared__ float red[4][256];
    __shared__ float s1[256], s2[128], s3[64];
    int b = blockIdx.x;
    int tid = threadIdx.x;
    int c = tid & 255, sg = tid >> 8;
    float a = 0.f;
    for (int s = sg; s < SPLITS; s += 4)
        a += partials[((size_t)s * BGR + b) * 256 + c];
    red[sg][c] = a;
    __syncthreads();
    if (tid < 256) {
        float v = red[0][tid] + red[1][tid] + red[2][tid] + red[3][tid] + lb1[tid];
        s1[tid] = v > 0.f ? v : 0.f;
    }
    __syncthreads();
    if (tid < 128) {
        float acc = lb2[tid];
        for (int k = 0; k < 256; k++) acc += s1[k] * lw2[k * 128 + tid];
        s2[tid] = acc > 0.f ? acc : 0.f;
    }
    __syncthreads();
    if (tid < 64) {
        float acc = lb3[tid];
        for (int k = 0; k < 128; k++) acc += s2[k] * lw3[k * 64 + tid];
        s3[tid] = acc > 0.f ? acc : 0.f;
    }
    __syncthreads();
    if (tid < 32) {
        float acc = lb4[tid];
        for (int k = 0; k < 64; k++) acc += s3[k] * lw4[k * 32 + tid];
        out[b * 32 + tid] = acc;
    }
}

extern "C" void kernel_launch(void* const* d_in, const int* in_sizes, int n_in,
                              void* d_out, int out_size, void* d_ws, size_t ws_size,
                              hipStream_t stream) {
    const float* x   = (const float*)d_in[0];
    const int* edge  = (const int*)d_in[1];
    const float* W1  = (const float*)d_in[2];
    const float* g1  = (const float*)d_in[4];
    const float* be1 = (const float*)d_in[5];
    const float* W2  = (const float*)d_in[6];
    const float* g2  = (const float*)d_in[8];
    const float* be2 = (const float*)d_in[9];
    const float* W3  = (const float*)d_in[10];
    const float* g3  = (const float*)d_in[12];
    const float* be3 = (const float*)d_in[13];
    const float* lw1 = (const float*)d_in[14];
    const float* lb1 = (const float*)d_in[15];
    const float* lw2 = (const float*)d_in[16];
    const float* lb2 = (const float*)d_in[17];
    const float* lw3 = (const float*)d_in[18];
    const float* lb3 = (const float*)d_in[19];
    const float* lw4 = (const float*)d_in[20];
    const float* lb4 = (const float*)d_in[21];

    const int E = in_sizes[1] / 2;
    const int N = NNODES;
    const int B = in_sizes[0] / (N * 3);
    const int NB = B * N;

    char* ws = (char*)d_ws;
    size_t bufBytes = (size_t)NB * HDIM * sizeof(float);   // 38.4 MB
    float* bufA  = (float*)ws;                  // agg1 / agg3
    float* bufB  = (float*)(ws + bufBytes);     // agg2 / partials (19.2 MB)
    char* p = ws + 2 * bufBytes;
    float* dis    = (float*)p;                 p += (size_t)N * 4;
    int*   deg    = (int*)p;                   p += (size_t)N * 4;
    int*   offs   = (int*)p;                   p += (size_t)(N + 1) * 4;
    int*   cursor = (int*)p;                   p += (size_t)N * 4;
    int*   csr_row= (int*)p;                   p += (size_t)E * 4;
    float* csr_w  = (float*)p;                 p += (size_t)E * 4;
    float* stats  = (float*)p;                 p += 48 * 4;
    float* stats1 = stats, *stats2 = stats + 16, *stats3 = stats + 32;
    float* partials = bufB;

    const int T = 256;
    dim3 gatherGrid((N + T - 1) / T, B / 4);

    hipMemsetAsync(deg, 0, (size_t)N * 4, stream);
    hipMemsetAsync(stats, 0, 48 * 4, stream);
    count_deg_kernel<<<(E + T - 1) / T, T, 0, stream>>>(edge + E, E, deg);
    make_dis_kernel<<<(N + T - 1) / T, T, 0, stream>>>(deg, dis, N);
    scan_kernel<<<1, 1024, 0, stream>>>(deg, offs, cursor, N);
    fill_csr_kernel<<<(E + T - 1) / T, T, 0, stream>>>(edge, edge + E, dis, cursor, csr_row, csr_w, E);

    // layer 1: agg1 = gather(x @ W1) -> bufA, stats1
    gatherF_kernel<3, false><<<gatherGrid, T, 0, stream>>>(
        x, W1, nullptr, nullptr, nullptr, offs, csr_row, csr_w, dis, bufA, stats1, N, NB);
    // layer 2: agg2 = gather(relu(bn1(agg1)) @ W2) -> bufB, stats2
    gatherF_kernel<6, true><<<gatherGrid, T, 0, stream>>>(
        bufA, W2, stats1, g1, be1, offs, csr_row, csr_w, dis, bufB, stats2, N, NB);
    // layer 3: agg3 = gather(relu(bn2(agg2)) @ W3) -> bufA, stats3
    gatherF_kernel<6, true><<<gatherGrid, T, 0, stream>>>(
        bufB, W3, stats2, g2, be2, offs, csr_row, csr_w, dis, bufA, stats3, N, NB);

    // MLP head
    gemm1_kernel<<<SPLITS, T, 0, stream>>>(bufA, stats3, g3, be3, lw1, partials, NB);
    tail_kernel<<<B, 1024, 0, stream>>>(partials, lb1, lw2, lb2, lw3, lb3, lw4, lb4, (float*)d_out);
}

// Round 4
// 465.100 us; speedup vs baseline: 10.9957x; 1.4741x over previous
//
#include <hip/hip_runtime.h>

#define NNODES 50000
#define BGR 32
#define ROWF 192              // 32 graphs * 6 channels, one node row
#define BN_EPS 1e-5f
#define NC 50                 // nodes per gemm1 block -> 300 k-values
#define GSPLITS (NNODES / NC) // 1000
#define RGROUPS 16
#define GATHER_BLOCKS 1024

// ---------- degree / normalization ----------
__global__ void count_deg_kernel(const int* __restrict__ col, int E, int* __restrict__ deg) {
    int e = blockIdx.x * blockDim.x + threadIdx.x;
    if (e < E) atomicAdd(&deg[col[e]], 1);
}

__global__ void make_dis_kernel(const int* __restrict__ deg, float* __restrict__ dis, int N) {
    int n = blockIdx.x * blockDim.x + threadIdx.x;
    if (n < N) dis[n] = rsqrtf((float)(deg[n] + 1));   // +1 self loop
}

// ---------- 3-phase scan: deg -> offs (exclusive), cursor copy ----------
__global__ __launch_bounds__(256) void scanA_kernel(const int* __restrict__ deg, int* __restrict__ bsum, int N) {
    __shared__ int lds[256];
    int i = blockIdx.x * 256 + threadIdx.x;
    lds[threadIdx.x] = (i < N) ? deg[i] : 0;
    __syncthreads();
    for (int off = 128; off > 0; off >>= 1) {
        if (threadIdx.x < off) lds[threadIdx.x] += lds[threadIdx.x + off];
        __syncthreads();
    }
    if (threadIdx.x == 0) bsum[blockIdx.x] = lds[0];
}

__global__ __launch_bounds__(256) void scanB_kernel(const int* __restrict__ bsum, int* __restrict__ bbase,
                                                    int* __restrict__ offsN, int nblk) {
    __shared__ int lds[256];
    int t = threadIdx.x;
    int v = (t < nblk) ? bsum[t] : 0;
    lds[t] = v;
    __syncthreads();
    for (int off = 1; off < 256; off <<= 1) {
        int u = (t >= off) ? lds[t - off] : 0;
        __syncthreads();
        lds[t] += u;
        __syncthreads();
    }
    if (t < nblk) bbase[t] = lds[t] - v;   // exclusive base per block
    if (t == 255) offsN[0] = lds[255];     // total -> offs[N]
}

__global__ __launch_bounds__(256) void scanC_kernel(const int* __restrict__ deg, const int* __restrict__ bbase,
                                                    int* __restrict__ offs, int* __restrict__ cursor, int N) {
    __shared__ int lds[256];
    int i = blockIdx.x * 256 + threadIdx.x;
    int t = threadIdx.x;
    int v = (i < N) ? deg[i] : 0;
    lds[t] = v;
    __syncthreads();
    for (int off = 1; off < 256; off <<= 1) {
        int u = (t >= off) ? lds[t - off] : 0;
        __syncthreads();
        lds[t] += u;
        __syncthreads();
    }
    if (i < N) {
        int excl = bbase[blockIdx.x] + lds[t] - v;
        offs[i] = excl;
        cursor[i] = excl;
    }
}

// ---------- CSR fill: (src, weight) packed 8B per edge, grouped by dest ----------
__global__ void fill_csr_kernel(const int* __restrict__ row, const int* __restrict__ col,
                                const float* __restrict__ dis, int* __restrict__ cursor,
                                int2* __restrict__ csr_rw, int E) {
    int e = blockIdx.x * blockDim.x + threadIdx.x;
    if (e >= E) return;
    int r = row[e], c = col[e];
    int pos = atomicAdd(&cursor[c], 1);
    csr_rw[pos] = make_int2(r, __float_as_int(dis[r] * dis[c]));
}

// ---------- T1: x [B][N][3] -> m1 [N][32*6] node-major, m1 = x @ W1 ----------
__global__ __launch_bounds__(256) void t1_kernel(const float* __restrict__ x,
                                                 const float* __restrict__ W,
                                                 float* __restrict__ m, int N) {
    __shared__ float xt[BGR][ROWF];   // 64 nodes * 3 floats per graph = 24KB
    __shared__ float sW[18];
    int tid = threadIdx.x;
    if (tid < 18) sW[tid] = W[tid];
    int n0 = blockIdx.x * 64;
    int nval = N - n0; if (nval > 64) nval = 64;
    int lim = nval * 3;
    for (int b = 0; b < BGR; b++) {
        if (tid < lim) xt[b][tid] = x[((size_t)b * N + n0) * 3 + tid];
    }
    __syncthreads();
    for (int i = 0; i < 8; i++) {
        int pi = i * 256 + tid;
        int nl = pi >> 5, b = pi & 31;
        if (nl < nval) {
            float h0 = xt[b][nl * 3], h1 = xt[b][nl * 3 + 1], h2 = xt[b][nl * 3 + 2];
            float* mp = m + (size_t)(n0 + nl) * ROWF + b * 6;
            #pragma unroll
            for (int j = 0; j < 6; j++)
                mp[j] = h0 * sW[j] + h1 * sW[6 + j] + h2 * sW[12 + j];
        }
    }
}

// ---------- T2/T3: in-place node-major  buf = relu(bn(buf)) @ W ----------
__global__ __launch_bounds__(256) void t23_kernel(float* buf,
                                                  const float* __restrict__ stats,
                                                  const float* __restrict__ gam,
                                                  const float* __restrict__ bet,
                                                  const float* __restrict__ W, int NB) {
    __shared__ float sW[36];
    int tid = threadIdx.x;
    if (tid < 36) sW[tid] = W[tid];
    __syncthreads();
    float inv = 1.f / (float)NB;
    float sa[6], sc[6];
    #pragma unroll
    for (int j = 0; j < 6; j++) {
        float mu = stats[j] * inv;
        float var = stats[6 + j] * inv - mu * mu;
        float rs = rsqrtf(var + BN_EPS);
        float a = gam[j] * rs;
        sa[j] = a; sc[j] = bet[j] - mu * a;
    }
    size_t i = (size_t)blockIdx.x * 256 + tid;   // (n,b) pair; addr i*6 == n*192+b*6
    if (i >= (size_t)NB) return;
    float* p = buf + i * 6;
    float2 a0 = *(float2*)p, a1 = *(float2*)(p + 2), a2 = *(float2*)(p + 4);
    float h[6] = {a0.x, a0.y, a1.x, a1.y, a2.x, a2.y};
    #pragma unroll
    for (int k = 0; k < 6; k++) {
        float v = fmaf(sa[k], h[k], sc[k]);
        h[k] = v > 0.f ? v : 0.f;
    }
    float o[6];
    #pragma unroll
    for (int j = 0; j < 6; j++) {
        float t = 0.f;
        #pragma unroll
        for (int k = 0; k < 6; k++) t = fmaf(h[k], sW[k * 6 + j], t);
        o[j] = t;
    }
    *(float2*)p = make_float2(o[0], o[1]);
    *(float2*)(p + 2) = make_float2(o[2], o[3]);
    *(float2*)(p + 4) = make_float2(o[4], o[5]);
}

// ---------- gather: wave-per-node SpMM over 768B rows; fused BN stats ----------
__global__ __launch_bounds__(256) void gather_kernel(const float* __restrict__ m,
                                                     const int* __restrict__ offs,
                                                     const int2* __restrict__ csr_rw,
                                                     const float* __restrict__ dis,
                                                     float* __restrict__ agg,
                                                     float* __restrict__ stats_out, int N) {
    int tid = threadIdx.x;
    int wv = tid >> 6, lane = tid & 63;
    bool lact = lane < 48;                       // 48 lanes x float4 = 192 floats
    float4 ssum = make_float4(0.f, 0.f, 0.f, 0.f);
    float4 ssq  = make_float4(0.f, 0.f, 0.f, 0.f);
    int ngrp = (N + 3) >> 2;
    for (int grp = blockIdx.x; grp < ngrp; grp += gridDim.x) {
        int n = grp * 4 + wv;
        if (n >= N) continue;
        float4 acc = make_float4(0.f, 0.f, 0.f, 0.f);
        float d = dis[n];
        int s = offs[n], e = offs[n + 1];
        int r = n;
        float w0 = d * d;                        // self-loop first
        for (int p = s; ; p++) {
            int2 rwn = make_int2(0, 0);
            if (p < e) rwn = csr_rw[p];          // prefetch next edge
            if (lact) {
                const float4 v = *(const float4*)(m + (size_t)r * ROWF + lane * 4);
                acc.x = fmaf(w0, v.x, acc.x);
                acc.y = fmaf(w0, v.y, acc.y);
                acc.z = fmaf(w0, v.z, acc.z);
                acc.w = fmaf(w0, v.w, acc.w);
            }
            if (p >= e) break;
            r = rwn.x;
            w0 = __int_as_float(rwn.y);
        }
        if (lact) *(float4*)(agg + (size_t)n * ROWF + lane * 4) = acc;
        ssum.x += acc.x; ssum.y += acc.y; ssum.z += acc.z; ssum.w += acc.w;
        ssq.x = fmaf(acc.x, acc.x, ssq.x); ssq.y = fmaf(acc.y, acc.y, ssq.y);
        ssq.z = fmaf(acc.z, acc.z, ssq.z); ssq.w = fmaf(acc.w, acc.w, ssq.w);
    }
    // lane l, comp q holds channel j=(4l+q)%6 : constant along lane stride 3
    float vals[8] = {ssum.x, ssum.y, ssum.z, ssum.w, ssq.x, ssq.y, ssq.z, ssq.w};
    #pragma unroll
    for (int q = 0; q < 8; q++) {
        vals[q] += __shfl_down(vals[q], 24, 64);
        vals[q] += __shfl_down(vals[q], 12, 64);
        vals[q] += __shfl_down(vals[q], 6, 64);
        vals[q] += __shfl_down(vals[q], 3, 64);
    }
    __shared__ float red[4][3][8];
    if (lane < 3) {
        #pragma unroll
        for (int q = 0; q < 8; q++) red[wv][lane][q] = vals[q];
    }
    __syncthreads();
    if (tid < 24) {
        int l0 = tid >> 3, qq = tid & 7;
        float v = red[0][l0][qq] + red[1][l0][qq] + red[2][l0][qq] + red[3][l0][qq];
        int j = (4 * l0 + (qq & 3)) % 6;
        atomicAdd(&stats_out[(qq < 4 ? 0 : 6) + j], v);
    }
}

// ---------- GEMM1: act[b][k]=BN3ReLU(agg3) node-major; waves own 8 graphs ----------
__global__ __launch_bounds__(256) void gemm1_kernel(const float* __restrict__ agg3,
                                                    const float* __restrict__ stats,
                                                    const float* __restrict__ gam,
                                                    const float* __restrict__ bet,
                                                    const float* __restrict__ lw1,
                                                    float* __restrict__ partials, int NB) {
    __shared__ float s_act[NC * ROWF];   // 9600 floats = 38.4KB
    int tid = threadIdx.x;
    float inv = 1.f / (float)NB;
    float sa[6], sc[6];
    #pragma unroll
    for (int j = 0; j < 6; j++) {
        float mu = stats[j] * inv;
        float var = stats[6 + j] * inv - mu * mu;
        float rs = rsqrtf(var + BN_EPS);
        float a = gam[j] * rs;
        sa[j] = a; sc[j] = bet[j] - mu * a;
    }
    int n0 = blockIdx.x * NC;
    for (int idx = tid; idx < NC * ROWF; idx += 256) {
        float v = agg3[(size_t)n0 * ROWF + idx];
        int j = idx % 6;
        float t = fmaf(sa[j], v, sc[j]);
        s_act[idx] = t > 0.f ? t : 0.f;
    }
    __syncthreads();
    int wv = tid >> 6, lane = tid & 63;
    int b0 = wv * 8;
    float4 acc[8];
    #pragma unroll
    for (int i = 0; i < 8; i++) acc[i] = make_float4(0.f, 0.f, 0.f, 0.f);
    const float* wbase = lw1 + (size_t)n0 * 6 * 256 + 4 * lane;
    for (int nl = 0; nl < NC; nl++) {
        float4 w6[6];
        #pragma unroll
        for (int j = 0; j < 6; j++)
            w6[j] = *(const float4*)(wbase + ((size_t)nl * 6 + j) * 256);
        const float* hb = &s_act[nl * ROWF + b0 * 6];
        #pragma unroll
        for (int bb = 0; bb < 8; bb++) {
            const float* hp = hb + bb * 6;
            float2 h01 = *(const float2*)hp;
            float2 h23 = *(const float2*)(hp + 2);
            float2 h45 = *(const float2*)(hp + 4);
            float4 a = acc[bb];
            a.x = fmaf(h01.x, w6[0].x, a.x); a.y = fmaf(h01.x, w6[0].y, a.y);
            a.z = fmaf(h01.x, w6[0].z, a.z); a.w = fmaf(h01.x, w6[0].w, a.w);
            a.x = fmaf(h01.y, w6[1].x, a.x); a.y = fmaf(h01.y, w6[1].y, a.y);
            a.z = fmaf(h01.y, w6[1].z, a.z); a.w = fmaf(h01.y, w6[1].w, a.w);
            a.x = fmaf(h23.x, w6[2].x, a.x); a.y = fmaf(h23.x, w6[2].y, a.y);
            a.z = fmaf(h23.x, w6[2].z, a.z); a.w = fmaf(h23.x, w6[2].w, a.w);
            a.x = fmaf(h23.y, w6[3].x, a.x); a.y = fmaf(h23.y, w6[3].y, a.y);
            a.z = fmaf(h23.y, w6[3].z, a.z); a.w = fmaf(h23.y, w6[3].w, a.w);
            a.x = fmaf(h45.x, w6[4].x, a.x); a.y = fmaf(h45.x, w6[4].y, a.y);
            a.z = fmaf(h45.x, w6[4].z, a.z); a.w = fmaf(h45.x, w6[4].w, a.w);
            a.x = fmaf(h45.y, w6[5].x, a.x); a.y = fmaf(h45.y, w6[5].y, a.y);
            a.z = fmaf(h45.y, w6[5].z, a.z); a.w = fmaf(h45.y, w6[5].w, a.w);
            acc[bb] = a;
        }
    }
    #pragma unroll
    for (int bb = 0; bb < 8; bb++)
        *(float4*)&partials[(((size_t)blockIdx.x * BGR) + b0 + bb) * 256 + 4 * lane] = acc[bb];
}

// ---------- reduce partials[GSPLITS][32*256] -> p2[RGROUPS][32*256] ----------
__global__ __launch_bounds__(256) void reduce1_kernel(const float* __restrict__ partials,
                                                      float* __restrict__ p2) {
    int o = blockIdx.x * 256 + threadIdx.x;   // grid.x = 32 -> 8192 outputs
    int g = blockIdx.y;                        // 0..15
    float a = 0.f;
    for (int s = g; s < GSPLITS; s += RGROUPS)
        a += partials[(size_t)s * (BGR * 256) + o];
    p2[g * (BGR * 256) + o] = a;
}

// ---------- tail: sum 16 groups + lb1/relu, then 256->128->64->32 ----------
__global__ __launch_bounds__(1024) void tail_kernel(const float* __restrict__ p2,
                                                    const float* __restrict__ lb1,
                                                    const float* __restrict__ lw2, const float* __restrict__ lb2,
                                                    const float* __restrict__ lw3, const float* __restrict__ lb3,
                                                    const float* __restrict__ lw4, const float* __restrict__ lb4,
                                                    float* __restrict__ out) {
    __shared__ float red[4][256];
    __shared__ float s1[256], s2[128], s3[64];
    int b = blockIdx.x;
    int tid = threadIdx.x;
    int c = tid & 255, sg = tid >> 8;
    float a = 0.f;
    for (int g = sg; g < RGROUPS; g += 4)
        a += p2[g * (BGR * 256) + b * 256 + c];
    red[sg][c] = a;
    __syncthreads();
    if (tid < 256) {
        float v = red[0][tid] + red[1][tid] + red[2][tid] + red[3][tid] + lb1[tid];
        s1[tid] = v > 0.f ? v : 0.f;
    }
    __syncthreads();
    if (tid < 128) {
        float acc = lb2[tid];
        for (int k = 0; k < 256; k++) acc += s1[k] * lw2[k * 128 + tid];
        s2[tid] = acc > 0.f ? acc : 0.f;
    }
    __syncthreads();
    if (tid < 64) {
        float acc = lb3[tid];
        for (int k = 0; k < 128; k++) acc += s2[k] * lw3[k * 64 + tid];
        s3[tid] = acc > 0.f ? acc : 0.f;
    }
    __syncthreads();
    if (tid < 32) {
        float acc = lb4[tid];
        for (int k = 0; k < 64; k++) acc += s3[k] * lw4[k * 32 + tid];
        out[b * 32 + tid] = acc;
    }
}

extern "C" void kernel_launch(void* const* d_in, const int* in_sizes, int n_in,
                              void* d_out, int out_size, void* d_ws, size_t ws_size,
                              hipStream_t stream) {
    const float* x   = (const float*)d_in[0];
    const int* edge  = (const int*)d_in[1];
    const float* W1  = (const float*)d_in[2];
    const float* g1  = (const float*)d_in[4];
    const float* be1 = (const float*)d_in[5];
    const float* W2  = (const float*)d_in[6];
    const float* g2  = (const float*)d_in[8];
    const float* be2 = (const float*)d_in[9];
    const float* W3  = (const float*)d_in[10];
    const float* g3  = (const float*)d_in[12];
    const float* be3 = (const float*)d_in[13];
    const float* lw1 = (const float*)d_in[14];
    const float* lb1 = (const float*)d_in[15];
    const float* lw2 = (const float*)d_in[16];
    const float* lb2 = (const float*)d_in[17];
    const float* lw3 = (const float*)d_in[18];
    const float* lb3 = (const float*)d_in[19];
    const float* lw4 = (const float*)d_in[20];
    const float* lb4 = (const float*)d_in[21];

    const int E = in_sizes[1] / 2;
    const int N = NNODES;
    const int B = in_sizes[0] / (N * 3);
    const int NB = B * N;
    const int nblk = (N + 255) / 256;

    char* ws = (char*)d_ws;
    size_t bufBytes = (size_t)N * ROWF * sizeof(float);   // 38.4 MB
    float* buf0 = (float*)ws;
    float* buf1 = (float*)(ws + bufBytes);
    char* p = ws + 2 * bufBytes;
    float* dis    = (float*)p;  p += (size_t)N * 4;
    int*   deg    = (int*)p;    p += (size_t)N * 4;
    int*   offs   = (int*)p;    p += (size_t)(N + 1) * 4;
    int*   cursor = (int*)p;    p += (size_t)N * 4;
    int*   bsum   = (int*)p;    p += 256 * 4;
    int*   bbase  = (int*)p;    p += 256 * 4;
    int2*  csr_rw = (int2*)p;   p += (size_t)E * 8;
    float* stats  = (float*)p;  p += 48 * 4;
    float* p2     = (float*)p;  p += (size_t)RGROUPS * BGR * 256 * 4;
    float* stats1 = stats, *stats2 = stats + 16, *stats3 = stats + 32;
    float* partials = buf0;    // gemm1 reads buf1, writes buf0 (32.8MB <= 38.4MB)

    const int T = 256;

    hipMemsetAsync(deg, 0, (size_t)N * 4, stream);
    hipMemsetAsync(stats, 0, 48 * 4, stream);
    count_deg_kernel<<<(E + T - 1) / T, T, 0, stream>>>(edge + E, E, deg);
    make_dis_kernel<<<(N + T - 1) / T, T, 0, stream>>>(deg, dis, N);
    scanA_kernel<<<nblk, T, 0, stream>>>(deg, bsum, N);
    scanB_kernel<<<1, T, 0, stream>>>(bsum, bbase, offs + N, nblk);
    scanC_kernel<<<nblk, T, 0, stream>>>(deg, bbase, offs, cursor, N);
    fill_csr_kernel<<<(E + T - 1) / T, T, 0, stream>>>(edge, edge + E, dis, cursor, csr_rw, E);

    // layer 1: m1 = x@W1 -> buf0 ; agg1 = S m1 -> buf1 (+stats1)
    t1_kernel<<<(N + 63) / 64, T, 0, stream>>>(x, W1, buf0, N);
    gather_kernel<<<GATHER_BLOCKS, T, 0, stream>>>(buf0, offs, csr_rw, dis, buf1, stats1, N);
    // layer 2: m2 = T(agg1) in-place buf1 ; agg2 -> buf0 (+stats2)
    t23_kernel<<<(NB + T - 1) / T, T, 0, stream>>>(buf1, stats1, g1, be1, W2, NB);
    gather_kernel<<<GATHER_BLOCKS, T, 0, stream>>>(buf1, offs, csr_rw, dis, buf0, stats2, N);
    // layer 3: m3 = T(agg2) in-place buf0 ; agg3 -> buf1 (+stats3)
    t23_kernel<<<(NB + T - 1) / T, T, 0, stream>>>(buf0, stats2, g2, be2, W3, NB);
    gather_kernel<<<GATHER_BLOCKS, T, 0, stream>>>(buf0, offs, csr_rw, dis, buf1, stats3, N);

    // MLP head
    gemm1_kernel<<<GSPLITS, T, 0, stream>>>(buf1, stats3, g3, be3, lw1, partials, NB);
    reduce1_kernel<<<dim3(32, RGROUPS), T, 0, stream>>>(partials, p2);
    tail_kernel<<<B, 1024, 0, stream>>>(p2, lb1, lw2, lb2, lw3, lb3, lw4, lb4, (float*)d_out);
}